// Round 6
// baseline (77.390 us; speedup 1.0000x reference)
//
#include <hip/hip_runtime.h>

typedef float v2f __attribute__((ext_vector_type(2)));

#define BB 8192
#define NN 36
#define INF_ 8
#define HH 8
#define DHH 9
#define GATF 72
#define ACTF 10
#define NTH 320
#define HSTRIDE 12
#define WSTRIDE 12
#define L2E 1.44269504088896f

static __device__ __forceinline__ v2f mk2(float a, float b) { v2f r; r.x = a; r.y = b; return r; }

__global__ __launch_bounds__(NTH, 6) void gnn_kernel(
    const float* __restrict__ x, const int* __restrict__ adj,
    const float* __restrict__ W, const float* __restrict__ a_src,
    const float* __restrict__ a_dst, const float* __restrict__ W_down,
    const float* __restrict__ b_down, const float* __restrict__ W_mu,
    const float* __restrict__ b_mu, float* __restrict__ out)
{
    const int b = blockIdx.x;
    const int tid = threadIdx.x;

    __shared__ float xcs[NN * 9];                        // xc, stride 9
    __shared__ float ts[NN];                             // t = x[:,:,4]
    __shared__ __align__(16) float hbuf[HH * NN * HSTRIDE];   // 13824 B
    __shared__ __align__(16) float edl[HH * NN];         // ed * log2e
    __shared__ uint2 adjm[NN];                           // row bitmasks
    __shared__ float pd[NN * 9];                         // partial down [i][h]
    __shared__ float feat[GATF];
    __shared__ __align__(16) float wlds[HH * 7 * WSTRIDE];   // W rows 16B-aligned
    __shared__ v2f  aid[HH * DHH];                       // {a_src, a_dst} interleaved
    __shared__ float wdlds[GATF];
    __shared__ float wmulds[GATF * ACTF];
    __shared__ float bdlds[1];
    __shared__ float bmulds[ACTF];

    // ---- Phase 0: stage inputs ----
    const float* xb = x + (size_t)b * (NN * INF_);
    if (tid < NN * INF_) {
        int n = tid >> 3, c = tid & 7;
        float v = xb[tid];
        if (c < 3) xcs[n * 9 + c] = v;
        else if (c > 3) xcs[n * 9 + (c - 1)] = v;
        if (c == 4) ts[n] = v;
    }
    {   // adjacency -> 36 row bitmasks on threads 256..291
        int i0 = tid - 256;
        if (i0 >= 0 && i0 < NN) {
            const int4* ap = reinterpret_cast<const int4*>(adj + i0 * NN);
            unsigned int lo = 0u, hi = 0u;
            #pragma unroll
            for (int q = 0; q < 9; ++q) {
                int4 a4 = ap[q];
                const int base = q * 4;
                if (base + 0 < 32) { lo |= (a4.x > 0 ? 1u << (base + 0) : 0u); } else { hi |= (a4.x > 0 ? 1u << (base - 32) : 0u); }
                if (base + 1 < 32) { lo |= (a4.y > 0 ? 1u << (base + 1) : 0u); } else { hi |= (a4.y > 0 ? 1u << (base + 1 - 32) : 0u); }
                if (base + 2 < 32) { lo |= (a4.z > 0 ? 1u << (base + 2) : 0u); } else { hi |= (a4.z > 0 ? 1u << (base + 2 - 32) : 0u); }
                if (base + 3 < 32) { lo |= (a4.w > 0 ? 1u << (base + 3) : 0u); } else { hi |= (a4.w > 0 ? 1u << (base + 3 - 32) : 0u); }
            }
            adjm[i0] = make_uint2(lo, hi);
        }
    }
    for (int idx = tid; idx < HH * 7 * DHH; idx += NTH) {
        int row = idx / DHH, d = idx - row * DHH;
        wlds[row * WSTRIDE + d] = W[idx];
    }
    if (tid < HH * DHH) aid[tid] = mk2(a_src[tid], a_dst[tid]);
    if (tid >= 128 && tid < 128 + GATF) wdlds[tid - 128] = W_down[tid - 128];
    for (int idx = tid; idx < GATF * ACTF; idx += NTH) wmulds[idx] = W_mu[idx];
    if (tid == 0) bdlds[0] = b_down[0];
    if (tid >= 64 && tid < 64 + ACTF) bmulds[tid - 64] = b_mu[tid - 64];
    __syncthreads();

    // ---- Phase 1+2: per (h,i) row: h-row (packed fma), es (reg), ed (LDS) ----
    const int hh = (tid < HH * NN) ? (tid / NN) : 0;
    const int i  = (tid < HH * NN) ? (tid - hh * NN) : 0;
    float esr = 0.f;
    if (tid < HH * NN) {
        const float* xp = xcs + i * 9;
        const float* wp = wlds + hh * 7 * WSTRIDE;
        v2f h01 = mk2(0.f, 0.f), h23 = h01, h45 = h01, h67 = h01;
        float h8 = 0.f;
        #pragma unroll
        for (int k = 0; k < 7; ++k) {
            float xk = xp[k];
            v2f xkk = mk2(xk, xk);
            const float* wr = wp + k * WSTRIDE;
            float4 wa = *reinterpret_cast<const float4*>(wr);
            float4 wb = *reinterpret_cast<const float4*>(wr + 4);
            float  wc = wr[8];
            h01 = __builtin_elementwise_fma(xkk, mk2(wa.x, wa.y), h01);
            h23 = __builtin_elementwise_fma(xkk, mk2(wa.z, wa.w), h23);
            h45 = __builtin_elementwise_fma(xkk, mk2(wb.x, wb.y), h45);
            h67 = __builtin_elementwise_fma(xkk, mk2(wb.z, wb.w), h67);
            h8 = fmaf(xk, wc, h8);
        }
        float* hp = hbuf + (hh * NN + i) * HSTRIDE;
        *reinterpret_cast<float4*>(hp)     = make_float4(h01.x, h01.y, h23.x, h23.y);
        *reinterpret_cast<float4*>(hp + 4) = make_float4(h45.x, h45.y, h67.x, h67.y);
        hp[8] = h8;
        const v2f* ap = aid + hh * DHH;
        v2f sd = mk2(0.f, 0.f);
        sd = __builtin_elementwise_fma(mk2(h01.x, h01.x), ap[0], sd);
        sd = __builtin_elementwise_fma(mk2(h01.y, h01.y), ap[1], sd);
        sd = __builtin_elementwise_fma(mk2(h23.x, h23.x), ap[2], sd);
        sd = __builtin_elementwise_fma(mk2(h23.y, h23.y), ap[3], sd);
        sd = __builtin_elementwise_fma(mk2(h45.x, h45.x), ap[4], sd);
        sd = __builtin_elementwise_fma(mk2(h45.y, h45.y), ap[5], sd);
        sd = __builtin_elementwise_fma(mk2(h67.x, h67.x), ap[6], sd);
        sd = __builtin_elementwise_fma(mk2(h67.y, h67.y), ap[7], sd);
        sd = __builtin_elementwise_fma(mk2(h8, h8), ap[8], sd);
        esr = sd.x * L2E;
        edl[hh * NN + i] = sd.y * L2E;
    }
    __syncthreads();

    // ---- Phase 3: attention row + PV + ELU + fused down partial ----
    if (tid < HH * NN) {
        const uint2 mrow = adjm[i];
        const float* hrow = hbuf + (hh * NN) * HSTRIDE;
        const float* edp = edl + hh * NN;
        const v2f esr2 = mk2(esr, esr);
        const v2f c02 = mk2(0.2f, 0.2f);
        v2f acc01 = mk2(0.f, 0.f), acc23 = acc01, acc45 = acc01, acc67 = acc01;
        float acc8 = 0.f;
        v2f ssum2 = mk2(0.f, 0.f);

#define PVE(jj, p_) { \
        const float* hj_ = hrow + (jj) * HSTRIDE; \
        float4 ha_ = *reinterpret_cast<const float4*>(hj_); \
        float4 hb_ = *reinterpret_cast<const float4*>(hj_ + 4); \
        float  hc_ = hj_[8]; \
        v2f pp_ = mk2(p_, p_); \
        acc01 = __builtin_elementwise_fma(pp_, mk2(ha_.x, ha_.y), acc01); \
        acc23 = __builtin_elementwise_fma(pp_, mk2(ha_.z, ha_.w), acc23); \
        acc45 = __builtin_elementwise_fma(pp_, mk2(hb_.x, hb_.y), acc45); \
        acc67 = __builtin_elementwise_fma(pp_, mk2(hb_.z, hb_.w), acc67); \
        acc8 = fmaf(p_, hc_, acc8); }

        // pair step: 2 j's; jb and jb+1 never straddle the 32-bit word boundary
#define STEP2(jb, w_, ee2_) { \
        v2f s2_ = esr2 + (ee2_); \
        v2f t2_ = s2_ * c02; \
        float p0_ = __builtin_exp2f(fmaxf(s2_.x, t2_.x)); \
        float p1_ = __builtin_exp2f(fmaxf(s2_.y, t2_.y)); \
        int m0_ = ((int)((w_) << (31 - ((jb) & 31)))) >> 31; \
        int m1_ = ((int)((w_) << (31 - (((jb) & 31) + 1)))) >> 31; \
        p0_ = __int_as_float(__float_as_int(p0_) & m0_); \
        p1_ = __int_as_float(__float_as_int(p1_) & m1_); \
        ssum2 += mk2(p0_, p1_); \
        PVE((jb), p0_); \
        PVE((jb) + 1, p1_); }

        #pragma unroll
        for (int q = 0; q < 9; ++q) {
            float4 e4 = *reinterpret_cast<const float4*>(edp + q * 4);  // broadcast
            const unsigned wq = (q < 8) ? mrow.x : mrow.y;
            STEP2(4 * q + 0, wq, mk2(e4.x, e4.y));
            STEP2(4 * q + 2, wq, mk2(e4.z, e4.w));
        }
#undef STEP2
#undef PVE

        float ssum = ssum2.x + ssum2.y;
        float inv = 1.0f / ssum;
        v2f inv2 = mk2(inv, inv);
        v2f o01 = acc01 * inv2, o23 = acc23 * inv2, o45 = acc45 * inv2, o67 = acc67 * inv2;
        float o8 = acc8 * inv;
        const float* wdp = wdlds + hh * DHH;
        float pdown = 0.f;
#define EPI(oval, dd_) { \
        float o_ = (oval); \
        o_ = (o_ > 0.f) ? o_ : (__builtin_exp2f(o_ * L2E) - 1.0f); \
        pdown = fmaf(o_, wdp[dd_], pdown); }
        EPI(o01.x, 0); EPI(o01.y, 1); EPI(o23.x, 2); EPI(o23.y, 3);
        EPI(o45.x, 4); EPI(o45.y, 5); EPI(o67.x, 6); EPI(o67.y, 7);
        EPI(o8, 8);
#undef EPI
        pd[i * 9 + hh] = pdown;
    }
    __syncthreads();

    // ---- Phase 4: down + feat = leaky_relu(concat(down, t), 0.01) ----
    if (tid < NN) {
        const float* pp = pd + tid * 9;
        float acc = bdlds[0];
        #pragma unroll
        for (int h = 0; h < HH; ++h) acc += pp[h];
        feat[tid] = (acc > 0.f) ? acc : 0.01f * acc;
    } else if (tid < 2 * NN) {
        float v = ts[tid - NN];
        feat[tid] = (v > 0.f) ? v : 0.01f * v;
    }
    __syncthreads();

    // ---- Phase 5: mu = feat @ W_mu + b_mu ----
    if (tid < ACTF) {
        float acc = bmulds[tid];
        #pragma unroll
        for (int k = 0; k < GATF; ++k) acc += feat[k] * wmulds[k * ACTF + tid];
        out[(size_t)b * ACTF + tid] = acc;
    }
}

extern "C" void kernel_launch(void* const* d_in, const int* in_sizes, int n_in,
                              void* d_out, int out_size, void* d_ws, size_t ws_size,
                              hipStream_t stream) {
    const float* x      = (const float*)d_in[0];
    const int*   adj    = (const int*)d_in[1];
    const float* W      = (const float*)d_in[2];
    const float* a_src  = (const float*)d_in[3];
    const float* a_dst  = (const float*)d_in[4];
    const float* W_down = (const float*)d_in[5];
    const float* b_down = (const float*)d_in[6];
    const float* W_mu   = (const float*)d_in[7];
    const float* b_mu   = (const float*)d_in[8];
    float* out = (float*)d_out;

    gnn_kernel<<<BB, NTH, 0, stream>>>(x, adj, W, a_src, a_dst, W_down, b_down, W_mu, b_mu, out);
}